// Round 2
// baseline (353.138 us; speedup 1.0000x reference)
//
#include <hip/hip_runtime.h>
#include <math.h>

// ---------------- problem constants ----------------
#define TARGET_SCALE 0.06f
constexpr int N_ = 8, S_ = 2048, C_ = 4, V_ = 128, K_ = 512;
constexpr int NS = N_ * S_;       // 16384 (n,s) pairs
constexpr int NQ = NS * C_;       // 65536 queries

// output layout (floats, concatenated in reference return order)
constexpr int O_DISC = 0;                  // [N,S,C,V]
constexpr int O_IDX  = NQ * V_;
constexpr int O_VQ   = O_IDX + NQ;
constexpr int O_ENC  = O_VQ + NQ;
constexpr int O_ENT  = O_ENC + NQ;         // scalar

// workspace layout (floats)
constexpr int WS_EMB  = 0;                 // normalized emb, C*K*V
constexpr int WS_E2   = C_ * K_ * V_;      // e2 per code, C*K
constexpr int WS_HIST = WS_E2 + C_ * K_;   // 512 bins

// ---------------- tiling ----------------
constexpr int QB  = 64;    // queries per block tile
constexpr int KCH = 128;   // codes per k-chunk (4 chunks)
constexpr int VCH = 32;    // v per chunk (4 chunks)
constexpr int LSP = 36;    // padded LDS row stride (floats) for 32-float chunks

// =====================================================================
// Kernel 1: normalize embeddings, e2, zero histogram
// =====================================================================
__global__ __launch_bounds__(256) void prep_emb(const float* __restrict__ emb0,
                                                float* __restrict__ ws) {
    const int wave = threadIdx.x >> 6;
    const int lane = threadIdx.x & 63;
    const int row  = blockIdx.x * 4 + wave;            // 0..2047 = c*512+k
    const float tn = TARGET_SCALE * sqrtf((float)V_);

    float2 e = *(const float2*)(emb0 + row * V_ + lane * 2);
    float ss = e.x * e.x + e.y * e.y;
    #pragma unroll
    for (int off = 32; off; off >>= 1) ss += __shfl_xor(ss, off);
    const float nrm = sqrtf(ss);

    float2 en;
    en.x = (tn * e.x) / nrm;    // mimic reference elementwise mul-then-div
    en.y = (tn * e.y) / nrm;
    *(float2*)(ws + WS_EMB + row * V_ + lane * 2) = en;

    float s2 = en.x * en.x + en.y * en.y;
    #pragma unroll
    for (int off = 32; off; off >>= 1) s2 += __shfl_xor(s2, off);
    if (lane == 0) ws[WS_E2 + row] = s2;

    if (blockIdx.x == 0) {   // zero histogram (ws is poisoned every launch)
        ws[WS_HIST + threadIdx.x]       = 0.f;
        ws[WS_HIST + 256 + threadIdx.x] = 0.f;
    }
}

// =====================================================================
// Kernel 2: distances + argmin + all per-query outputs
// grid: (NS/QB, C) = (256,4) blocks, one tile each -> exactly 4 blocks/CU.
// block: 256 threads = 8 qg x 32 kg; thread tile 8q x 4k (32 accs).
// LDS ~29.4 KiB; __launch_bounds__(256,4) -> 4 blocks/CU, 16 waves/CU.
// =====================================================================
__global__ __launch_bounds__(256, 4) void vq_main(const float* __restrict__ x0,
                                                  float* __restrict__ ws,
                                                  float* __restrict__ out) {
    __shared__ float ES[KCH * LSP];    // 18432 B: code chunk (128 x 32v)
    __shared__ float XS[QB * LSP];     //  9216 B: x0 chunk  (64 x 32v)
    __shared__ float s_scale[QB];
    __shared__ float s_x2[QB];
    __shared__ float s_es2[KCH];
    __shared__ int   s_bestk[QB];

    const int c      = blockIdx.y;
    const int tid    = threadIdx.x;
    const int kg     = tid & 31;        // 0..31
    const int qg     = tid >> 5;        // 0..7
    const int nsBase = blockIdx.x * QB;
    const float tn   = TARGET_SCALE * sqrtf((float)V_);

    const float* __restrict__ embc = ws + WS_EMB + c * K_ * V_;
    const float* __restrict__ e2c  = ws + WS_E2 + c * K_;
    float* __restrict__ hist = ws + WS_HIST;

    // ---- pass 1: per-row norm -> scale, x2 (reads x0 from global) ----
    {
        const int row = tid >> 2, j = tid & 3;
        const float* xr = x0 + ((size_t)(nsBase + row) * C_ + c) * V_ + j * 32;
        float ss = 0.f;
        #pragma unroll
        for (int m = 0; m < 8; ++m) {
            float4 v = *(const float4*)(xr + m * 4);
            ss += v.x * v.x + v.y * v.y + v.z * v.z + v.w * v.w;
        }
        ss += __shfl_xor(ss, 1);
        ss += __shfl_xor(ss, 2);
        const float scale = tn / sqrtf(ss);
        float x2 = 0.f;
        #pragma unroll
        for (int m = 0; m < 8; ++m) {
            float4 v = *(const float4*)(xr + m * 4);
            float a = scale * v.x, b = scale * v.y, d = scale * v.z, e = scale * v.w;
            x2 += a * a + b * b + d * d + e * e;
        }
        x2 += __shfl_xor(x2, 1);
        x2 += __shfl_xor(x2, 2);
        if (j == 0) { s_scale[row] = scale; s_x2[row] = x2; }
    }

    // ---- k-chunk loop with running argmin ----
    float bd[8]; int bk[8];
    #pragma unroll
    for (int qq = 0; qq < 8; ++qq) { bd[qq] = 3.4e38f; bk[qq] = 0x7fffffff; }

    for (int kc = 0; kc < K_ / KCH; ++kc) {
        float acc[8][4];
        #pragma unroll
        for (int qq = 0; qq < 8; ++qq)
            #pragma unroll
            for (int kk = 0; kk < 4; ++kk) acc[qq][kk] = 0.f;

        for (int vc = 0; vc < V_ / VCH; ++vc) {
            __syncthreads();   // everyone done reading previous chunk (or pass-1 LDS writes visible)
            // stage E chunk: 128 rows x 32 v  (4 float4 per thread)
            #pragma unroll
            for (int it = 0; it < 4; ++it) {
                int fi = tid + 256 * it;            // 0..1023
                int r = fi >> 3, slot = fi & 7;
                float4 v = *(const float4*)(embc + (size_t)(kc * KCH + r) * V_ + vc * VCH + slot * 4);
                *(float4*)(ES + r * LSP + slot * 4) = v;
            }
            // stage X chunk: 64 rows x 32 v (2 float4 per thread)
            #pragma unroll
            for (int it = 0; it < 2; ++it) {
                int fi = tid + 256 * it;            // 0..511
                int r = fi >> 3, slot = fi & 7;
                float4 v = *(const float4*)(x0 + ((size_t)(nsBase + r) * C_ + c) * V_ + vc * VCH + slot * 4);
                *(float4*)(XS + r * LSP + slot * 4) = v;
            }
            if (vc == 0 && tid < KCH) s_es2[tid] = e2c[kc * KCH + tid];
            __syncthreads();

            // compute: 8 vq steps, each 12 LDS f4 reads -> 128 FMAs
            #pragma unroll
            for (int vq = 0; vq < 8; ++vq) {
                float4 ev[4], xv[8];
                #pragma unroll
                for (int kk = 0; kk < 4; ++kk)
                    ev[kk] = *(const float4*)(ES + (kg + 32 * kk) * LSP + vq * 4);
                #pragma unroll
                for (int qq = 0; qq < 8; ++qq)
                    xv[qq] = *(const float4*)(XS + (qg + 8 * qq) * LSP + vq * 4);
                #pragma unroll
                for (int qq = 0; qq < 8; ++qq)
                    #pragma unroll
                    for (int kk = 0; kk < 4; ++kk) {
                        acc[qq][kk] = fmaf(xv[qq].x, ev[kk].x, acc[qq][kk]);
                        acc[qq][kk] = fmaf(xv[qq].y, ev[kk].y, acc[qq][kk]);
                        acc[qq][kk] = fmaf(xv[qq].z, ev[kk].z, acc[qq][kk]);
                        acc[qq][kk] = fmaf(xv[qq].w, ev[kk].w, acc[qq][kk]);
                    }
            }
        }

        // fold chunk into running argmin: d2 = (x2+e2) - 2*scale*acc
        #pragma unroll
        for (int kk = 0; kk < 4; ++kk) {
            const int kloc  = kg + 32 * kk;
            const float e2v = s_es2[kloc];
            const int kglob = kc * KCH + kloc;
            #pragma unroll
            for (int qq = 0; qq < 8; ++qq) {
                const int ql = qg + 8 * qq;
                const float xe = s_scale[ql] * acc[qq][kk];
                const float d  = fmaf(-2.f, xe, s_x2[ql] + e2v);
                if (d < bd[qq]) { bd[qq] = d; bk[qq] = kglob; }
            }
        }
    }

    // ---- cross-kg argmin reduce (32 lanes share qg), tie -> lower k ----
    #pragma unroll
    for (int off = 16; off; off >>= 1) {
        #pragma unroll
        for (int qq = 0; qq < 8; ++qq) {
            float od = __shfl_xor(bd[qq], off);
            int   ok = __shfl_xor(bk[qq], off);
            if (od < bd[qq] || (od == bd[qq] && ok < bk[qq])) { bd[qq] = od; bk[qq] = ok; }
        }
    }
    if (kg == 0) {
        #pragma unroll
        for (int qq = 0; qq < 8; ++qq) s_bestk[qg + 8 * qq] = bk[qq];
    }
    __syncthreads();

    // ---- epilogue: 4 threads per query, x0/emb from global (L2-hot) ----
    {
        const int q = tid >> 2, j = tid & 3;
        const int kstar   = s_bestk[q];
        const float scale = s_scale[q];
        const size_t qglob = (size_t)(nsBase + q) * C_ + c;
        const float* er = embc + (size_t)kstar * V_ + j * 32;
        const float* xr = x0 + qglob * V_ + j * 32;
        float* dr = out + O_DISC + qglob * V_ + j * 32;
        float vqp = 0.f, en2 = 0.f;
        #pragma unroll
        for (int m = 0; m < 8; ++m) {
            float4 e4 = *(const float4*)(er + m * 4);
            float4 x4 = *(const float4*)(xr + m * 4);
            float xa = scale * x4.x, xb = scale * x4.y, xc = scale * x4.z, xd = scale * x4.w;
            float da = xa - e4.x, db = xb - e4.y, dc = xc - e4.z, dd = xd - e4.w;
            vqp += da * da + db * db + dc * dc + dd * dd;
            float ga = xa - x4.x, gb = xb - x4.y, gc = xc - x4.z, gd = xd - x4.w;
            en2 += ga * ga + gb * gb + gc * gc + gd * gd;
            *(float4*)(dr + m * 4) = e4;   // discrete == chosen code row
        }
        vqp += __shfl_xor(vqp, 1);
        vqp += __shfl_xor(vqp, 2);
        en2 += __shfl_xor(en2, 1);
        en2 += __shfl_xor(en2, 2);
        if (j == 0) {
            out[O_IDX + qglob] = (float)(kstar + c * K_);
            out[O_VQ  + qglob] = vqp;
            out[O_ENC + qglob] = vqp + en2;
            atomicAdd(hist + kstar, 1.0f);
        }
    }
}

// =====================================================================
// Kernel 3: entropy over 512-bin histogram
// NOTE: reference divides by N*S (=16384), NOT by N*S*C. prob sums to 4.
// =====================================================================
__global__ __launch_bounds__(256) void entropy_k(const float* __restrict__ ws,
                                                 float* __restrict__ out) {
    const float* hist = ws + WS_HIST;
    const int t = threadIdx.x;
    float s = 0.f;
    for (int i = t; i < K_; i += 256) {
        float h = hist[i];
        if (h > 0.f) {
            float p = h / (float)NS;     // <-- 16384, matches reference
            s += p * logf(p);
        }
    }
    #pragma unroll
    for (int off = 32; off; off >>= 1) s += __shfl_xor(s, off);
    __shared__ float wsum[4];
    if ((t & 63) == 0) wsum[t >> 6] = s;
    __syncthreads();
    if (t == 0) out[O_ENT] = -(wsum[0] + wsum[1] + wsum[2] + wsum[3]);
}

// =====================================================================
extern "C" void kernel_launch(void* const* d_in, const int* in_sizes, int n_in,
                              void* d_out, int out_size, void* d_ws, size_t ws_size,
                              hipStream_t stream) {
    const float* x0   = (const float*)d_in[0];
    const float* emb0 = (const float*)d_in[1];
    float* out = (float*)d_out;
    float* ws  = (float*)d_ws;

    prep_emb<<<512, 256, 0, stream>>>(emb0, ws);
    vq_main<<<dim3(NS / QB, C_), 256, 0, stream>>>(x0, ws, out);
    entropy_k<<<1, 256, 0, stream>>>(ws, out);
}